// Round 2
// baseline (5895.234 us; speedup 1.0000x reference)
//
#include <hip/hip_runtime.h>
#include <stdint.h>

// LSTM: B=256, T=512, D=128, H=512, C=10
// R11 = dual-stream latency hiding. R10's data-as-flag regressed (poll
// traffic tripled FETCH, iteration latency grew) -> revert to R9's proven
// flag sync, and instead HIDE the exchange latency: each group runs TWO
// independent 16-batch streams in alternating phases. While stream A's
// h(t+1) propagates through the MALL, the wave computes stream B's phase.
// Structure: 8 groups x 16 blocks x 4 waves = 64 waves/group; wave owns
// 8 hidden units (32 gate rows = 2 MFMA row-tiles), K=640 per stream.
// Phase: h-MFMA (operands preloaded last phase) -> gates -> publish h ->
// poll other stream's flags (spin covers our store-ack) -> vmcnt(0) ->
// flag -> issue other stream's h loads -> xp-MFMA -> X prefetch.
// Speculative flag read at phase top usually skips the spin entirely.

#define T_STEPS 512
#define BATCH   256
#define DIM     128
#define HID     512
#define NGRP    8

typedef _Float16 half8 __attribute__((ext_vector_type(8)));
typedef float    f32x4 __attribute__((ext_vector_type(4)));
typedef float    f32x2 __attribute__((ext_vector_type(2)));

#define SLOT_HALFS (BATCH * HID)
#define FLG_OFF    (2 * SLOT_HALFS * 2)            // 524288 B (2 slots)
#define WS_NEEDED  (FLG_OFF + NGRP * 2 * 64 * 4)   // + flag arrays

__device__ __forceinline__ half8 cvt8(f32x4 a, f32x4 b) {
  half8 r;
  r[0]=(_Float16)a[0]; r[1]=(_Float16)a[1]; r[2]=(_Float16)a[2]; r[3]=(_Float16)a[3];
  r[4]=(_Float16)b[0]; r[5]=(_Float16)b[1]; r[6]=(_Float16)b[2]; r[7]=(_Float16)b[3];
  return r;
}
__device__ __forceinline__ half8 load8_cvt(const float* p) {
  const f32x4* q = (const f32x4*)p;
  return cvt8(q[0], q[1]);
}
__device__ __forceinline__ float fsig(float x) {
  return __builtin_amdgcn_rcpf(1.f + __expf(-x));
}
__device__ __forceinline__ float ftanh(float x) {
  return 1.f - 2.f * __builtin_amdgcn_rcpf(1.f + __expf(2.f * x));
}

union h2u { unsigned u; _Float16 h[2]; };
union h8u { unsigned long long u2[2]; half8 h; };

// One phase of one stream. S=0: polls other stream's flags at target t
// (2 phases of slack). S=1: polls at target t+1 (1 phase of slack).
template<int S>
__device__ __forceinline__ void phase(
    const int t, const int lane, const int q, const int J, const int wid,
    const int bMy, const int bOth,
    const half8 (&whh)[16][2], const half8 (&wih)[4][2],
    const float (&bias)[2][4],
    f32x4 (&acc)[2], float (&c_st)[2], float (&hsum)[2],
    f32x4 (&xraw)[8], const float* __restrict__ Xb,
    _Float16* __restrict__ hbuf,
    unsigned* __restrict__ flgMine, unsigned* __restrict__ flgOth,
    unsigned long long (&lo)[16], unsigned long long (&hi)[16])
{
  const int  tgt     = (S == 0) ? t : (t + 1);
  const bool doPoll  = (S == 0) ? (t >= 1) : (t + 1 < T_STEPS);
  const bool notLast = (t + 1 < T_STEPS);

  // speculative early flag read -- wait sinks to the check far below
  unsigned ev = 0xFFFFFFFFu;
  if (doPoll)
    ev = __hip_atomic_load(flgOth + lane, __ATOMIC_RELAXED,
                           __HIP_MEMORY_SCOPE_AGENT);

  // h-MFMAs: consume h_S(t) fragments preloaded during the previous phase
  if (t > 0) {
    #pragma unroll
    for (int kc = 0; kc < 16; ++kc) {
      h8u u; u.u2[0] = lo[kc]; u.u2[1] = hi[kc];
      acc[0] = __builtin_amdgcn_mfma_f32_16x16x32_f16(whh[kc][0], u.h, acc[0], 0, 0, 0);
      acc[1] = __builtin_amdgcn_mfma_f32_16x16x32_f16(whh[kc][1], u.h, acc[1], 0, 0, 0);
    }
  }

  // gates: lane owns units u0=J+2q, u1=J+2q+1 for batch bMy.
  // acc[0] rows: i(u0), f(u0), i(u1), f(u1); acc[1]: g(u0), o(u0), g(u1), o(u1)
  h2u hv;
  {
    const float i0 = fsig (acc[0][0] + bias[0][0]);
    const float f0 = fsig (acc[0][1] + bias[0][1]);
    const float g0 = ftanh(acc[1][0] + bias[1][0]);
    const float o0 = fsig (acc[1][1] + bias[1][1]);
    const float c0 = f0 * c_st[0] + i0 * g0;
    c_st[0] = c0;
    const float h0 = o0 * ftanh(c0);
    hsum[0] += h0;
    const float i1 = fsig (acc[0][2] + bias[0][2]);
    const float f1 = fsig (acc[0][3] + bias[0][3]);
    const float g1 = ftanh(acc[1][2] + bias[1][2]);
    const float o1 = fsig (acc[1][3] + bias[1][3]);
    const float c1 = f1 * c_st[1] + i1 * g1;
    c_st[1] = c1;
    const float h1 = o1 * ftanh(c1);
    hsum[1] += h1;
    hv.h[0] = (_Float16)h0; hv.h[1] = (_Float16)h1;
  }

  // publish h_S(t+1): one 4B relaxed agent store
  if (notLast) {
    unsigned* hw = (unsigned*)(hbuf + (size_t)((t + 1) & 1) * SLOT_HALFS
                               + (size_t)bMy * HID + J + 2 * q);
    __hip_atomic_store(hw, hv.u, __ATOMIC_RELAXED, __HIP_MEMORY_SCOPE_AGENT);
  }

  // poll other stream's flags (spin time covers our store-ack drain)
  if (doPoll) {
    if (!__all((int)(ev >= (unsigned)tgt))) {
      for (;;) {
        unsigned v = __hip_atomic_load(flgOth + lane, __ATOMIC_RELAXED,
                                       __HIP_MEMORY_SCOPE_AGENT);
        if (__all((int)(v >= (unsigned)tgt))) break;
      }
    }
    __builtin_amdgcn_sched_barrier(0);  // nothing crosses the flag check
  }

  // manual release: drain (near-free after the poll), then per-wave flag
  if (notLast) {
    asm volatile("s_waitcnt vmcnt(0)" ::: "memory");
    if (lane == 0)
      __hip_atomic_store(flgMine + wid, (unsigned)(t + 1), __ATOMIC_RELAXED,
                         __HIP_MEMORY_SCOPE_AGENT);
  }

  // issue other stream's h(tgt) loads -- consumed next phase; latency
  // hides under xp-MFMA + X prefetch + next phase's entry
  if (doPoll) {
    const unsigned long long* hp = (const unsigned long long*)
        (hbuf + (size_t)(tgt & 1) * SLOT_HALFS + (size_t)bOth * HID) + q * 2;
    #pragma unroll
    for (int kc = 0; kc < 16; ++kc) {
      lo[kc] = __hip_atomic_load(hp + kc * 8,     __ATOMIC_RELAXED, __HIP_MEMORY_SCOPE_AGENT);
      hi[kc] = __hip_atomic_load(hp + kc * 8 + 1, __ATOMIC_RELAXED, __HIP_MEMORY_SCOPE_AGENT);
    }
  }

  // xp(t+1) for this stream + X(t+2) prefetch (propagation window)
  if (notLast) {
    #pragma unroll
    for (int mt = 0; mt < 2; ++mt) acc[mt] = (f32x4){0.f, 0.f, 0.f, 0.f};
    #pragma unroll
    for (int xc = 0; xc < 4; ++xc) {
      half8 xb = cvt8(xraw[2 * xc], xraw[2 * xc + 1]);
      acc[0] = __builtin_amdgcn_mfma_f32_16x16x32_f16(wih[xc][0], xb, acc[0], 0, 0, 0);
      acc[1] = __builtin_amdgcn_mfma_f32_16x16x32_f16(wih[xc][1], xb, acc[1], 0, 0, 0);
    }
    const int tn = (t + 2 < T_STEPS) ? (t + 2) : (T_STEPS - 1);
    const float* xp = Xb + (size_t)tn * DIM + q * 8;
    #pragma unroll
    for (int xc = 0; xc < 4; ++xc) {
      const f32x4* src = (const f32x4*)(xp + xc * 32);
      xraw[2 * xc]     = src[0];
      xraw[2 * xc + 1] = src[1];
    }
  }
}

__global__ __launch_bounds__(256, 1) void lstm_persistent(
    const float* __restrict__ X,   const float* __restrict__ Wih,
    const float* __restrict__ Whh, const float* __restrict__ bih,
    const float* __restrict__ bhh, const float* __restrict__ Wlin,
    float* __restrict__ out, _Float16* __restrict__ hbuf,
    unsigned* __restrict__ flg)
{
  const int tid  = threadIdx.x;
  const int w    = tid >> 6;
  const int lane = tid & 63;
  const int col  = lane & 15;        // batch-within-stream; W A-frag row
  const int q    = lane >> 4;        // 0..3
  const int bid  = blockIdx.x;
  const int g    = bid & 7;          // group (8 groups x 16 blocks)
  const int blk  = bid >> 3;         // 0..15 within group
  const int J    = blk * 32 + w * 8; // hidden-unit base owned by this wave
  const int wid  = blk * 4 + w;      // wave id in group, 0..63
  const int bA   = g * 32 + col;       // stream-0 batch
  const int bB   = g * 32 + 16 + col;  // stream-1 batch

  // ---- W fragments into registers (once) ----
  // A-frag row r'=col: unit J+(r'>>1), gate pair (r'&1); tile0={i,f}, tile1={g,o}
  half8 whh[16][2];
  half8 wih[4][2];
  const int gpair = col & 1, uoff = col >> 1;
  #pragma unroll
  for (int kc = 0; kc < 16; ++kc)
    #pragma unroll
    for (int mt = 0; mt < 2; ++mt) {
      const int row = (2 * mt + gpair) * HID + J + uoff;
      whh[kc][mt] = load8_cvt(Whh + (size_t)row * HID + kc * 32 + q * 8);
    }
  #pragma unroll
  for (int xc = 0; xc < 4; ++xc)
    #pragma unroll
    for (int mt = 0; mt < 2; ++mt) {
      const int row = (2 * mt + gpair) * HID + J + uoff;
      wih[xc][mt] = load8_cvt(Wih + (size_t)row * DIM + xc * 32 + q * 8);
    }

  float bias[2][4];
  #pragma unroll
  for (int mt = 0; mt < 2; ++mt)
    #pragma unroll
    for (int r = 0; r < 4; ++r) {
      const int row = (2 * mt + (r & 1)) * HID + J + 2 * q + (r >> 1);
      bias[mt][r] = bih[row] + bhh[row];
    }

  float cA[2] = {0.f, 0.f}, cB[2] = {0.f, 0.f};
  float hsA[2] = {0.f, 0.f}, hsB[2] = {0.f, 0.f};
  const float* XbA = X + (size_t)bA * T_STEPS * DIM;
  const float* XbB = X + (size_t)bB * T_STEPS * DIM;
  unsigned* flgA = flg + (g * 2 + 0) * 64;
  unsigned* flgB = flg + (g * 2 + 1) * 64;

  // ---- prologue: X(0) for both streams, acc = xp(0), prefetch X(1) ----
  f32x4 xrA[8], xrB[8];
  #pragma unroll
  for (int xc = 0; xc < 4; ++xc) {
    const f32x4* pa = (const f32x4*)(XbA + xc * 32 + q * 8);
    const f32x4* pb = (const f32x4*)(XbB + xc * 32 + q * 8);
    xrA[2 * xc] = pa[0]; xrA[2 * xc + 1] = pa[1];
    xrB[2 * xc] = pb[0]; xrB[2 * xc + 1] = pb[1];
  }
  f32x4 accA[2], accB[2];
  #pragma unroll
  for (int mt = 0; mt < 2; ++mt) {
    accA[mt] = (f32x4){0.f, 0.f, 0.f, 0.f};
    accB[mt] = (f32x4){0.f, 0.f, 0.f, 0.f};
  }
  #pragma unroll
  for (int xc = 0; xc < 4; ++xc) {
    half8 xa = cvt8(xrA[2 * xc], xrA[2 * xc + 1]);
    half8 xb = cvt8(xrB[2 * xc], xrB[2 * xc + 1]);
    #pragma unroll
    for (int mt = 0; mt < 2; ++mt) {
      accA[mt] = __builtin_amdgcn_mfma_f32_16x16x32_f16(wih[xc][mt], xa, accA[mt], 0, 0, 0);
      accB[mt] = __builtin_amdgcn_mfma_f32_16x16x32_f16(wih[xc][mt], xb, accB[mt], 0, 0, 0);
    }
  }
  #pragma unroll
  for (int xc = 0; xc < 4; ++xc) {
    const f32x4* pa = (const f32x4*)(XbA + (size_t)DIM + xc * 32 + q * 8);
    const f32x4* pb = (const f32x4*)(XbB + (size_t)DIM + xc * 32 + q * 8);
    xrA[2 * xc] = pa[0]; xrA[2 * xc + 1] = pa[1];
    xrB[2 * xc] = pb[0]; xrB[2 * xc + 1] = pb[1];
  }

  // shared h-fragment registers, reused by both streams alternately
  unsigned long long lo[16], hi[16];

  for (int t = 0; t < T_STEPS; ++t) {
    phase<0>(t, lane, q, J, wid, bA, bB, whh, wih, bias,
             accA, cA, hsA, xrA, XbA, hbuf, flgA, flgB, lo, hi);
    phase<1>(t, lane, q, J, wid, bB, bA, whh, wih, bias,
             accB, cB, hsB, xrB, XbB, hbuf, flgB, flgA, lo, hi);
  }

  // epilogue: logits += mean_h * W_lin^T (bias pre-set by init kernel)
  const float inv = 1.0f / (float)T_STEPS;
  #pragma unroll
  for (int cls = 0; cls < 10; ++cls) {
    const f32x2 wl = *(const f32x2*)(Wlin + (size_t)cls * HID + J + 2 * q);
    float pA = (hsA[0] * wl[0] + hsA[1] * wl[1]) * inv;
    float pB = (hsB[0] * wl[0] + hsB[1] * wl[1]) * inv;
    pA += __shfl_xor(pA, 16, 64);
    pA += __shfl_xor(pA, 32, 64);
    pB += __shfl_xor(pB, 16, 64);
    pB += __shfl_xor(pB, 32, 64);
    if (q == 0) {
      atomicAdd(out + bA * 10 + cls, pA);
      atomicAdd(out + bB * 10 + cls, pB);
    }
  }
}

__global__ void init_out(const float* __restrict__ blin, float* __restrict__ out) {
  const int i = blockIdx.x * blockDim.x + threadIdx.x;
  if (i < BATCH * 10) out[i] = blin[i % 10];
}

extern "C" void kernel_launch(void* const* d_in, const int* in_sizes, int n_in,
                              void* d_out, int out_size, void* d_ws, size_t ws_size,
                              hipStream_t stream) {
  const float* X    = (const float*)d_in[0];
  const float* Wih  = (const float*)d_in[1];
  const float* Whh  = (const float*)d_in[2];
  const float* bih  = (const float*)d_in[3];
  const float* bhh  = (const float*)d_in[4];
  const float* Wlin = (const float*)d_in[5];
  const float* blin = (const float*)d_in[6];
  float* out = (float*)d_out;

  if (ws_size < (size_t)WS_NEEDED) return;

  _Float16* hbuf = (_Float16*)d_ws;
  unsigned* flg  = (unsigned*)((char*)d_ws + FLG_OFF);

  // only flags need zeroing; hbuf reads are gated by flags
  hipMemsetAsync((char*)d_ws + FLG_OFF, 0, NGRP * 2 * 64 * 4, stream);
  init_out<<<10, 256, 0, stream>>>(blin, out);
  lstm_persistent<<<128, 256, 0, stream>>>(X, Wih, Whh, bih, bhh, Wlin, out,
                                           hbuf, flg);
}

// Round 3
// 2832.073 us; speedup vs baseline: 2.0816x; 2.0816x over previous
//
#include <hip/hip_runtime.h>
#include <stdint.h>

// LSTM: B=256, T=512, D=128, H=512, C=10
// R12 = R9 skeleton + LDS-shared h-broadcast + per-block flags.
// Cost model from R9/R10/R11: step ~ C1*(syncs) + C2*(uncached KB read per
// wave); C2 ~ 0.2us/KB dominates (32 waves each re-reading 16KB h(t)/step).
// Fix: the 4 waves of a block split the h(t) read 4 ways (64B/lane), stage
// in LDS, __syncthreads, ds_read full set. Uncached reads/wave: 16KB->4KB.
// Sync: per-BLOCK flags (8/group, one 128B line each; fan-in 32->8).
// Release: publish (8B sc1 store) -> __syncthreads (implicit vmcnt(0)
// drains all 4 waves' store acks) -> tid0 stores block flag. Own block's
// flag skipped in poll (data already ack'd at our barrier). X prefetched
// 2 steps ahead (double buffer), issued post-share-barrier so only the
// release barrier (~600cy later) can drain it -- polls stay clean.

#define T_STEPS 512
#define BATCH   256
#define DIM     128
#define HID     512
#define NGRP    16
#define BT      16

typedef _Float16 half8 __attribute__((ext_vector_type(8)));
typedef _Float16 half4 __attribute__((ext_vector_type(4)));
typedef float    f32x4 __attribute__((ext_vector_type(4)));
typedef unsigned u32x4 __attribute__((ext_vector_type(4)));

#define SLOT_HALFS (BATCH * HID)
#define FLG_OFF    (2 * SLOT_HALFS * 2)          // 524288 B (2 h slots)
#define WS_NEEDED  (FLG_OFF + NGRP * 8 * 128)    // 8 block-flag lines/group

__device__ __forceinline__ half8 cvt8(f32x4 a, f32x4 b) {
  half8 r;
  r[0]=(_Float16)a[0]; r[1]=(_Float16)a[1]; r[2]=(_Float16)a[2]; r[3]=(_Float16)a[3];
  r[4]=(_Float16)b[0]; r[5]=(_Float16)b[1]; r[6]=(_Float16)b[2]; r[7]=(_Float16)b[3];
  return r;
}
__device__ __forceinline__ half8 load8_cvt(const float* p) {
  const f32x4* q = (const f32x4*)p;
  return cvt8(q[0], q[1]);
}
__device__ __forceinline__ float fsig(float x) {
  return __builtin_amdgcn_rcpf(1.f + __expf(-x));
}
__device__ __forceinline__ float ftanh(float x) {
  return 1.f - 2.f * __builtin_amdgcn_rcpf(1.f + __expf(2.f * x));
}

union h4u { unsigned long long u; half4 h; };
union c16 { unsigned long long u2[2]; u32x4 v; };

__global__ __launch_bounds__(256, 1) void lstm_persistent(
    const float* __restrict__ X,   const float* __restrict__ Wih,
    const float* __restrict__ Whh, const float* __restrict__ bih,
    const float* __restrict__ bhh, const float* __restrict__ Wlin,
    float* __restrict__ out, _Float16* __restrict__ hbuf,
    unsigned* __restrict__ flg)
{
  // 16KB: h(t) of this group's 16 batches. u32 idx = kc*256 + col*16 + q*4
  __shared__ unsigned hsh[4096];

  const int tid  = threadIdx.x;
  const int w    = tid >> 6;
  const int lane = tid & 63;
  const int col  = lane & 15;        // batch-within-group; W A-frag row
  const int q    = lane >> 4;        // 0..3
  const int bid  = blockIdx.x;
  const int g    = bid & 15;         // group
  const int blk  = bid >> 4;         // 0..7 within group
  const int J    = blk * 64 + w * 16;   // hidden-unit base owned by this wave
  const int b_my = g * BT + col;     // this lane's batch

  // ---- W fragments into registers (once) ----
  half8 whh[16][4];                  // [k-chunk of 32][gate]
  half8 wih[4][4];
  #pragma unroll
  for (int kc = 0; kc < 16; ++kc)
    #pragma unroll
    for (int mt = 0; mt < 4; ++mt) {
      const int row = mt * HID + J + col;
      whh[kc][mt] = load8_cvt(Whh + (size_t)row * HID + kc * 32 + q * 8);
    }
  #pragma unroll
  for (int xc = 0; xc < 4; ++xc)
    #pragma unroll
    for (int mt = 0; mt < 4; ++mt) {
      const int row = mt * HID + J + col;
      wih[xc][mt] = load8_cvt(Wih + (size_t)row * DIM + xc * 32 + q * 8);
    }

  float bias[4][4], c_st[4], hsum[4];
  #pragma unroll
  for (int mt = 0; mt < 4; ++mt)
    #pragma unroll
    for (int r = 0; r < 4; ++r) {
      const int row = mt * HID + J + q * 4 + r;
      bias[mt][r] = bih[row] + bhh[row];
    }
  #pragma unroll
  for (int r = 0; r < 4; ++r) { c_st[r] = 0.f; hsum[r] = 0.f; }

  unsigned* gflg = flg + g * 8 * 32;   // 8 block-flags, 128B apart
  const float* Xb = X + (size_t)b_my * T_STEPS * DIM;

  // ---- prologue: acc = xp(0); prefetch X(1)->buf1, X(2)->buf0 ----
  f32x4 xr0[8], xr1[8];                // buf[k&1] holds X(k)
  #pragma unroll
  for (int xc = 0; xc < 4; ++xc) {
    const f32x4* p = (const f32x4*)(Xb + xc * 32 + q * 8);
    xr0[2 * xc] = p[0]; xr0[2 * xc + 1] = p[1];
  }
  f32x4 acc[4];
  #pragma unroll
  for (int mt = 0; mt < 4; ++mt) acc[mt] = (f32x4){0.f, 0.f, 0.f, 0.f};
  #pragma unroll
  for (int xc = 0; xc < 4; ++xc) {
    half8 xb = cvt8(xr0[2 * xc], xr0[2 * xc + 1]);
    #pragma unroll
    for (int mt = 0; mt < 4; ++mt)
      acc[mt] = __builtin_amdgcn_mfma_f32_16x16x32_f16(wih[xc][mt], xb, acc[mt], 0, 0, 0);
  }
  #pragma unroll
  for (int xc = 0; xc < 4; ++xc) {
    const f32x4* p1 = (const f32x4*)(Xb + (size_t)1 * DIM + xc * 32 + q * 8);
    const f32x4* p2 = (const f32x4*)(Xb + (size_t)2 * DIM + xc * 32 + q * 8);
    xr1[2 * xc] = p1[0]; xr1[2 * xc + 1] = p1[1];
    xr0[2 * xc] = p2[0]; xr0[2 * xc + 1] = p2[1];
  }

  for (int t = 0; t < T_STEPS; ++t) {
    if (t > 0) {
      // poll 8 block-flags (8 separate lines; skip own block -- our data
      // was ack'd at our release barrier, avoid a self round trip)
      {
        const int fl = lane & 7;
        for (;;) {
          unsigned v = __hip_atomic_load(gflg + fl * 32, __ATOMIC_RELAXED,
                                         __HIP_MEMORY_SCOPE_AGENT);
          if (fl == blk) v = 0xFFFFFFFFu;
          if (__all((int)(v >= (unsigned)t))) break;
        }
      }
      __builtin_amdgcn_sched_barrier(0);  // nothing crosses the spin

      // this wave's quarter of h(t): kc in [4w, 4w+4) -- 64B/lane
      unsigned long long lo[4], hi[4];
      {
        const unsigned long long* base = (const unsigned long long*)
            (hbuf + (size_t)(t & 1) * SLOT_HALFS + (size_t)b_my * HID);
        #pragma unroll
        for (int i = 0; i < 4; ++i) {
          const int kc = w * 4 + i;
          lo[i] = __hip_atomic_load(base + kc * 8 + q * 2,     __ATOMIC_RELAXED, __HIP_MEMORY_SCOPE_AGENT);
          hi[i] = __hip_atomic_load(base + kc * 8 + q * 2 + 1, __ATOMIC_RELAXED, __HIP_MEMORY_SCOPE_AGENT);
        }
      }
      // stage to LDS
      #pragma unroll
      for (int i = 0; i < 4; ++i) {
        const int kc = w * 4 + i;
        c16 u; u.u2[0] = lo[i]; u.u2[1] = hi[i];
        *(u32x4*)(hsh + kc * 256 + col * 16 + q * 4) = u.v;
      }
      __syncthreads();   // share barrier (drains ds_writes)

      // X(t+2) prefetch NOW -- only the release barrier (~600cy later)
      // can drain it; polls and slice-load waits stay clean
      {
        const int tn = (t + 2 < T_STEPS) ? (t + 2) : (T_STEPS - 1);
        const float* xp = Xb + (size_t)tn * DIM + q * 8;
        f32x4* dst = (t & 1) ? xr1 : xr0;   // buf[(t+2)&1] == buf[t&1]
        #pragma unroll
        for (int xc = 0; xc < 4; ++xc) {
          const f32x4* src = (const f32x4*)(xp + xc * 32);
          dst[2 * xc]     = src[0];
          dst[2 * xc + 1] = src[1];
        }
      }

      // full h(t) from LDS -> MFMA
      #pragma unroll
      for (int kc = 0; kc < 16; ++kc) {
        const half8 hb = *(const half8*)(hsh + kc * 256 + col * 16 + q * 4);
        #pragma unroll
        for (int mt = 0; mt < 4; ++mt)
          acc[mt] = __builtin_amdgcn_mfma_f32_16x16x32_f16(whh[kc][mt], hb, acc[mt], 0, 0, 0);
      }
    }

    // gates -> c,h ; each lane owns units J+q*4..+3 for batch col
    h4u hv;
    #pragma unroll
    for (int r = 0; r < 4; ++r) {
      const float ig = fsig(acc[0][r] + bias[0][r]);
      const float fg = fsig(acc[1][r] + bias[1][r]);
      const float gg = ftanh(acc[2][r] + bias[2][r]);
      const float og = fsig(acc[3][r] + bias[3][r]);
      const float cc = fg * c_st[r] + ig * gg;
      c_st[r] = cc;
      const float h = og * ftanh(cc);
      hsum[r] += h;
      hv.h[r] = (_Float16)h;
    }

    if (t + 1 < T_STEPS) {
      // publish h(t+1): one 8B relaxed agent store (fire-and-forget here;
      // the release barrier's implicit per-wave vmcnt(0) drains the ack)
      unsigned long long* hw =
          (unsigned long long*)(hbuf + (size_t)((t + 1) & 1) * SLOT_HALFS
                                + (size_t)b_my * HID + J + q * 4);
      __hip_atomic_store(hw, hv.u, __ATOMIC_RELAXED, __HIP_MEMORY_SCOPE_AGENT);

      // release barrier: all 4 waves' publishes ack'd after this
      __syncthreads();
      if (tid == 0)
        __hip_atomic_store(gflg + blk * 32, (unsigned)(t + 1),
                           __ATOMIC_RELAXED, __HIP_MEMORY_SCOPE_AGENT);

      // xp(t+1) MFMA from buf[(t+1)&1] (loaded 2 steps ago, long resident)
      #pragma unroll
      for (int mt = 0; mt < 4; ++mt) acc[mt] = (f32x4){0.f, 0.f, 0.f, 0.f};
      const f32x4* xbuf = ((t + 1) & 1) ? xr1 : xr0;
      #pragma unroll
      for (int xc = 0; xc < 4; ++xc) {
        half8 xb = cvt8(xbuf[2 * xc], xbuf[2 * xc + 1]);
        #pragma unroll
        for (int mt = 0; mt < 4; ++mt)
          acc[mt] = __builtin_amdgcn_mfma_f32_16x16x32_f16(wih[xc][mt], xb, acc[mt], 0, 0, 0);
      }
    }
  }

  // epilogue: logits += mean_h * W_lin^T (bias pre-set by init kernel)
  const float inv = 1.0f / (float)T_STEPS;
  float m[4];
  #pragma unroll
  for (int r = 0; r < 4; ++r) m[r] = hsum[r] * inv;
  #pragma unroll
  for (int cls = 0; cls < 10; ++cls) {
    f32x4 wl = *(const f32x4*)(Wlin + (size_t)cls * HID + J + q * 4);
    float p = m[0] * wl[0] + m[1] * wl[1] + m[2] * wl[2] + m[3] * wl[3];
    p += __shfl_xor(p, 16, 64);
    p += __shfl_xor(p, 32, 64);
    if (q == 0) atomicAdd(out + b_my * 10 + cls, p);
  }
}

__global__ void init_out(const float* __restrict__ blin, float* __restrict__ out) {
  const int i = blockIdx.x * blockDim.x + threadIdx.x;
  if (i < BATCH * 10) out[i] = blin[i % 10];
}

extern "C" void kernel_launch(void* const* d_in, const int* in_sizes, int n_in,
                              void* d_out, int out_size, void* d_ws, size_t ws_size,
                              hipStream_t stream) {
  const float* X    = (const float*)d_in[0];
  const float* Wih  = (const float*)d_in[1];
  const float* Whh  = (const float*)d_in[2];
  const float* bih  = (const float*)d_in[3];
  const float* bhh  = (const float*)d_in[4];
  const float* Wlin = (const float*)d_in[5];
  const float* blin = (const float*)d_in[6];
  float* out = (float*)d_out;

  if (ws_size < (size_t)WS_NEEDED) return;

  _Float16* hbuf = (_Float16*)d_ws;
  unsigned* flg  = (unsigned*)((char*)d_ws + FLG_OFF);

  // only flags need zeroing; hbuf reads are gated by flags
  hipMemsetAsync((char*)d_ws + FLG_OFF, 0, NGRP * 8 * 128, stream);
  init_out<<<10, 256, 0, stream>>>(blin, out);
  lstm_persistent<<<128, 256, 0, stream>>>(X, Wih, Whh, bih, bhh, Wlin, out,
                                           hbuf, flg);
}